// Round 1
// baseline (849.506 us; speedup 1.0000x reference)
//
#include <hip/hip_runtime.h>
#include <hip/hip_bf16.h>

#define NTOK 32768
#define NE 64
#define HD 1024
#define CAP 1280
#define NKF (NTOK*2)      // 65536 flat (token,k)
#define NSLOT (NE*CAP)    // 81920

typedef __attribute__((ext_vector_type(8))) short bf16x8;
typedef __attribute__((ext_vector_type(4))) float f32x4;
typedef __attribute__((ext_vector_type(4))) unsigned short u16x4;

__device__ __forceinline__ short f2bf(float f) {
  union { __hip_bfloat16 b; short s; } u;
  u.b = __float2bfloat16(f);
  return u.s;
}
__device__ __forceinline__ float bf2f(unsigned short h) {
  return __uint_as_float(((unsigned)h) << 16);
}

// ---------------- gating: logits[N,64] = x @ gw^T (fp32) ----------------
__global__ __launch_bounds__(256) void gating_kernel(const float* __restrict__ x,
                                                     const float* __restrict__ gw,
                                                     float* __restrict__ logits) {
  __shared__ float Xs[64][132];
  __shared__ float Gs[64][132];
  const int tid = threadIdx.x;
  const int tok0 = blockIdx.x * 64;
  const int th = tid >> 4;   // token sub-row 0..15; tokens th + i*16
  const int te = tid & 15;   // expert sub-col 0..15; experts te + j*16
  float acc[4][4];
#pragma unroll
  for (int i = 0; i < 4; ++i)
#pragma unroll
    for (int j = 0; j < 4; ++j) acc[i][j] = 0.f;

  for (int k0 = 0; k0 < HD; k0 += 128) {
#pragma unroll
    for (int r = 0; r < 8; ++r) {
      int idx = r * 256 + tid;
      int row = idx >> 5;
      int c = (idx & 31) * 4;
      *(float4*)&Xs[row][c] = *(const float4*)&x[(size_t)(tok0 + row) * HD + k0 + c];
      *(float4*)&Gs[row][c] = *(const float4*)&gw[(size_t)row * HD + k0 + c];
    }
    __syncthreads();
#pragma unroll 4
    for (int kk = 0; kk < 32; ++kk) {
      float4 xv[4], gv[4];
#pragma unroll
      for (int i = 0; i < 4; ++i) xv[i] = *(float4*)&Xs[th + i * 16][kk * 4];
#pragma unroll
      for (int j = 0; j < 4; ++j) gv[j] = *(float4*)&Gs[te + j * 16][kk * 4];
#pragma unroll
      for (int i = 0; i < 4; ++i)
#pragma unroll
        for (int j = 0; j < 4; ++j) {
          acc[i][j] = fmaf(xv[i].x, gv[j].x, acc[i][j]);
          acc[i][j] = fmaf(xv[i].y, gv[j].y, acc[i][j]);
          acc[i][j] = fmaf(xv[i].z, gv[j].z, acc[i][j]);
          acc[i][j] = fmaf(xv[i].w, gv[j].w, acc[i][j]);
        }
    }
    __syncthreads();
  }
#pragma unroll
  for (int i = 0; i < 4; ++i)
#pragma unroll
    for (int j = 0; j < 4; ++j)
      logits[(size_t)(tok0 + th + i * 16) * NE + te + j * 16] = acc[i][j];
}

// ---------------- top-2 + probs + importance partials ----------------
__global__ __launch_bounds__(256) void topk_kernel(const float* __restrict__ logits,
                                                   int2* __restrict__ e01,
                                                   float2* __restrict__ p01,
                                                   float* __restrict__ imp_part) {
  const int t = blockIdx.x * 256 + threadIdx.x;
  float l[64];
  const float4* lp = (const float4*)(logits + (size_t)t * NE);
#pragma unroll
  for (int i = 0; i < 16; ++i) {
    float4 v = lp[i];
    l[4 * i] = v.x; l[4 * i + 1] = v.y; l[4 * i + 2] = v.z; l[4 * i + 3] = v.w;
  }
  float v1 = -1e30f; int i1 = 0;
#pragma unroll
  for (int j = 0; j < 64; ++j) if (l[j] > v1) { v1 = l[j]; i1 = j; }
  float v2 = -1e30f; int i2 = 0;
#pragma unroll
  for (int j = 0; j < 64; ++j) if (j != i1 && l[j] > v2) { v2 = l[j]; i2 = j; }
  float ex = __expf(v2 - v1);
  float inv2 = 1.f / (1.f + ex);
  e01[t] = make_int2(i1, i2);
  p01[t] = make_float2(inv2, ex * inv2);

  float s = 0.f;
#pragma unroll
  for (int j = 0; j < 64; ++j) s += __expf(l[j] - v1);
  float invs = 1.f / s;
  const int wid = t >> 6;
#pragma unroll
  for (int e = 0; e < 64; ++e) {
    float p = __expf(l[e] - v1) * invs;
#pragma unroll
    for (int off = 32; off; off >>= 1) p += __shfl_xor(p, off);
    if ((threadIdx.x & 63) == 0) imp_part[(size_t)wid * 64 + e] = p;
  }
}

// ---------------- FCFS dispatch (stable per-expert positions) ----------------
__global__ __launch_bounds__(1024) void dispatch_kernel(const int2* __restrict__ e01,
                                                        int* __restrict__ slot_of,
                                                        int* __restrict__ slot_token,
                                                        int* __restrict__ counts) {
  __shared__ int wave_hist[16][64];
  __shared__ int running[64];
  const int tid = threadIdx.x;
  const int w = tid >> 6, lane = tid & 63;
  if (tid < 64) running[tid] = 0;
  __syncthreads();
  for (int tile = 0; tile < NKF / 1024; ++tile) {
    const int i = tile * 1024 + tid;
    int2 ee = e01[i >> 1];
    const int e = (i & 1) ? ee.y : ee.x;
    int rank = 0, cnt = 0;
#pragma unroll
    for (int j = 0; j < 64; ++j) {
      int ej = __shfl(e, j);
      rank += (j < lane) & (ej == e);
      cnt += (ej == lane);
    }
    wave_hist[w][lane] = cnt;
    __syncthreads();
    int pos = running[e] + rank;
#pragma unroll
    for (int ww = 0; ww < 16; ++ww)
      if (ww < w) pos += wave_hist[ww][e];
    int slot = (pos < CAP) ? (e * CAP + pos) : -1;
    slot_of[i] = slot;
    if (slot >= 0) slot_token[slot] = i;
    __syncthreads();
    if (tid < 64) {
      int tot = 0;
#pragma unroll
      for (int ww = 0; ww < 16; ++ww) tot += wave_hist[ww][tid];
      running[tid] += tot;
    }
    __syncthreads();
  }
  if (tid < 64) counts[tid] = running[tid];
}

// ---------------- gather tokens -> expert inputs (bf16) ----------------
__global__ __launch_bounds__(128) void gather_kernel(const float* __restrict__ x,
                                                     const int* __restrict__ slot_token,
                                                     __hip_bfloat16* __restrict__ xe) {
  const int slot = blockIdx.x;
  const int tid = threadIdx.x;
  const int i = slot_token[slot];
  __hip_bfloat16* dst = xe + (size_t)slot * HD;
  if (i < 0) {
    bf16x8 z = {};
    *(bf16x8*)(dst + tid * 8) = z;
  } else {
    const int tok = i >> 1;
    const float4* src = (const float4*)(x + (size_t)tok * HD);
    float4 a = src[tid * 2], b = src[tid * 2 + 1];
    bf16x8 o;
    o[0] = f2bf(a.x); o[1] = f2bf(a.y); o[2] = f2bf(a.z); o[3] = f2bf(a.w);
    o[4] = f2bf(b.x); o[5] = f2bf(b.y); o[6] = f2bf(b.z); o[7] = f2bf(b.w);
    *(bf16x8*)(dst + tid * 8) = o;
  }
}

// ---------------- convert expert_w -> bf16 ----------------
__global__ __launch_bounds__(256) void convw_kernel(const float* __restrict__ w,
                                                    __hip_bfloat16* __restrict__ wb) {
  const size_t idx = ((size_t)blockIdx.x * 256 + threadIdx.x) * 8;
  float4 a = *(const float4*)(w + idx);
  float4 b = *(const float4*)(w + idx + 4);
  bf16x8 o;
  o[0] = f2bf(a.x); o[1] = f2bf(a.y); o[2] = f2bf(a.z); o[3] = f2bf(a.w);
  o[4] = f2bf(b.x); o[5] = f2bf(b.y); o[6] = f2bf(b.z); o[7] = f2bf(b.w);
  *(bf16x8*)(wb + idx) = o;
}

// ---------------- grouped expert GEMM: eo[e,c,d] = sum_h xe[e,c,h]*wb[e,d,h] ----------------
#define ASYNC16(g, l) __builtin_amdgcn_global_load_lds( \
    (const __attribute__((address_space(1))) void*)(g), \
    (__attribute__((address_space(3))) void*)(l), 16, 0, 0)

__global__ __launch_bounds__(256) void moe_gemm_kernel(const __hip_bfloat16* __restrict__ Xe,
                                                       const __hip_bfloat16* __restrict__ Wb,
                                                       __hip_bfloat16* __restrict__ Eo) {
  __shared__ __hip_bfloat16 As[128 * 32];
  __shared__ __hip_bfloat16 Bs[128 * 32];
  const int e = blockIdx.y;
  const int tm = blockIdx.x >> 3;   // 10 M-tiles
  const int tn = blockIdx.x & 7;    // 8 N-tiles
  const int tid = threadIdx.x;
  const int lane = tid & 63;
  const int w = tid >> 6;
  const int wm = w >> 1, wn = w & 1;

  const __hip_bfloat16* A = Xe + (size_t)e * CAP * HD + (size_t)tm * 128 * HD;
  const __hip_bfloat16* B = Wb + (size_t)e * HD * HD + (size_t)tn * 128 * HD;

  const int srow = tid >> 2;          // 0..63
  const int scol = (tid & 3) * 8;     // bf16 elements
  const int ldsbase = (tid & 192) * 16;  // wave-uniform byte base

  f32x4 acc[4][4] = {};
  const int fr = lane & 15;
  const int fq = lane >> 4;

  for (int k0 = 0; k0 < HD; k0 += 32) {
    ASYNC16(A + (size_t)srow * HD + k0 + scol, (char*)As + ldsbase);
    ASYNC16(A + (size_t)(srow + 64) * HD + k0 + scol, (char*)As + 4096 + ldsbase);
    ASYNC16(B + (size_t)srow * HD + k0 + scol, (char*)Bs + ldsbase);
    ASYNC16(B + (size_t)(srow + 64) * HD + k0 + scol, (char*)Bs + 4096 + ldsbase);
    __syncthreads();
    bf16x8 af[4], bb[4];
#pragma unroll
    for (int m = 0; m < 4; ++m)
      af[m] = *(const bf16x8*)(As + (wm * 64 + m * 16 + fr) * 32 + fq * 8);
#pragma unroll
    for (int n = 0; n < 4; ++n)
      bb[n] = *(const bf16x8*)(Bs + (wn * 64 + n * 16 + fr) * 32 + fq * 8);
#pragma unroll
    for (int m = 0; m < 4; ++m)
#pragma unroll
      for (int n = 0; n < 4; ++n)
        acc[m][n] = __builtin_amdgcn_mfma_f32_16x16x32_bf16(af[m], bb[n], acc[m][n], 0, 0, 0);
    __syncthreads();
  }
  __hip_bfloat16* C = Eo + (size_t)e * CAP * HD + (size_t)(tm * 128 + wm * 64) * HD + tn * 128 + wn * 64;
#pragma unroll
  for (int m = 0; m < 4; ++m)
#pragma unroll
    for (int n = 0; n < 4; ++n)
#pragma unroll
      for (int r = 0; r < 4; ++r)
        C[(size_t)(m * 16 + fq * 4 + r) * HD + n * 16 + fr] = __float2bfloat16(acc[m][n][r]);
}

// ---------------- combine: out[t] = sum_k p_k * eo[slot_k] ----------------
__global__ __launch_bounds__(256) void combine_kernel(const __hip_bfloat16* __restrict__ eo,
                                                      const int* __restrict__ slot_of,
                                                      const float2* __restrict__ p01,
                                                      float* __restrict__ out) {
  const int t = blockIdx.x;
  const int tid = threadIdx.x;
  const float2 p = p01[t];
  const int s0 = slot_of[2 * t], s1 = slot_of[2 * t + 1];
  float a0 = 0.f, a1 = 0.f, a2 = 0.f, a3 = 0.f;
  if (s0 >= 0) {
    u16x4 v = *(const u16x4*)((const unsigned short*)eo + (size_t)s0 * HD + tid * 4);
    a0 += p.x * bf2f(v[0]); a1 += p.x * bf2f(v[1]);
    a2 += p.x * bf2f(v[2]); a3 += p.x * bf2f(v[3]);
  }
  if (s1 >= 0) {
    u16x4 v = *(const u16x4*)((const unsigned short*)eo + (size_t)s1 * HD + tid * 4);
    a0 += p.y * bf2f(v[0]); a1 += p.y * bf2f(v[1]);
    a2 += p.y * bf2f(v[2]); a3 += p.y * bf2f(v[3]);
  }
  float4 res = make_float4(a0, a1, a2, a3);
  *(float4*)(out + (size_t)t * HD + tid * 4) = res;
}

// ---------------- aux loss ----------------
__global__ __launch_bounds__(64) void aux_kernel(const float* __restrict__ imp_part,
                                                 const int* __restrict__ counts,
                                                 float* __restrict__ out) {
  const int e = threadIdx.x;  // 64 threads
  float imp = 0.f;
  for (int w = 0; w < 512; ++w) imp += imp_part[(size_t)w * 64 + e];
  imp *= (1.f / (float)NTOK);
  float usage = (float)counts[e] / (float)NKF;
  float v = usage * imp;
#pragma unroll
  for (int off = 32; off; off >>= 1) v += __shfl_xor(v, off);
  if (e == 0) out[(size_t)NTOK * HD] = fminf(v * (float)NE * 0.01f, 1.0f);
}

extern "C" void kernel_launch(void* const* d_in, const int* in_sizes, int n_in,
                              void* d_out, int out_size, void* d_ws, size_t ws_size,
                              hipStream_t stream) {
  const float* x = (const float*)d_in[0];
  const float* gw = (const float*)d_in[1];
  const float* ew = (const float*)d_in[2];
  float* out = (float*)d_out;

  char* p = (char*)d_ws;
  float* logits = (float*)p;            p += (size_t)NTOK * NE * 4;
  int2* e01 = (int2*)p;                 p += (size_t)NTOK * 8;
  float2* p01 = (float2*)p;             p += (size_t)NTOK * 8;
  int* slot_of = (int*)p;               p += (size_t)NKF * 4;
  int* slot_token = (int*)p;            p += (size_t)NSLOT * 4;
  int* counts = (int*)p;                p += 256;
  float* imp_part = (float*)p;          p += (size_t)512 * 64 * 4;
  __hip_bfloat16* Wb = (__hip_bfloat16*)p;  p += (size_t)NE * HD * HD * 2;
  __hip_bfloat16* Xe = (__hip_bfloat16*)p;  p += (size_t)NSLOT * HD * 2;
  __hip_bfloat16* Eo = (__hip_bfloat16*)p;  p += (size_t)NSLOT * HD * 2;

  hipMemsetAsync(slot_token, 0xFF, (size_t)NSLOT * 4, stream);

  convw_kernel<<<32768, 256, 0, stream>>>(ew, Wb);
  gating_kernel<<<NTOK / 64, 256, 0, stream>>>(x, gw, logits);
  topk_kernel<<<NTOK / 256, 256, 0, stream>>>(logits, e01, p01, imp_part);
  dispatch_kernel<<<1, 1024, 0, stream>>>(e01, slot_of, slot_token, counts);
  gather_kernel<<<NSLOT, 128, 0, stream>>>(x, slot_token, Xe);
  moe_gemm_kernel<<<dim3(80, 64), 256, 0, stream>>>(Xe, Wb, Eo);
  combine_kernel<<<NTOK, 256, 0, stream>>>(Eo, slot_of, p01, out);
  aux_kernel<<<1, 64, 0, stream>>>(imp_part, counts, out);
}

// Round 4
// 585.954 us; speedup vs baseline: 1.4498x; 1.4498x over previous
//
#include <hip/hip_runtime.h>
#include <hip/hip_bf16.h>

#define NTOK 32768
#define NE 64
#define HD 1024
#define CAP 1280
#define NKF (NTOK*2)      // 65536 flat (token,k)
#define NSLOT (NE*CAP)    // 81920
#define NTILE 256         // dispatch tiles of 256 items

typedef __attribute__((ext_vector_type(8))) short bf16x8;
typedef __attribute__((ext_vector_type(4))) float f32x4;
typedef __attribute__((ext_vector_type(4))) unsigned short u16x4;

__device__ __forceinline__ short f2bf(float f) {
  union { __hip_bfloat16 b; short s; } u;
  u.b = __float2bfloat16(f);
  return u.s;
}
__device__ __forceinline__ float bf2f(unsigned short h) {
  return __uint_as_float(((unsigned)h) << 16);
}

// ---------------- gating: logits[N,64] = x @ gw^T (fp32) ----------------
__global__ __launch_bounds__(256) void gating_kernel(const float* __restrict__ x,
                                                     const float* __restrict__ gw,
                                                     float* __restrict__ logits) {
  __shared__ float Xs[64][132];
  __shared__ float Gs[64][132];
  const int tid = threadIdx.x;
  const int tok0 = blockIdx.x * 64;
  const int th = tid >> 4;   // token sub-row 0..15
  const int te = tid & 15;   // expert sub-col 0..15
  float acc[4][4];
#pragma unroll
  for (int i = 0; i < 4; ++i)
#pragma unroll
    for (int j = 0; j < 4; ++j) acc[i][j] = 0.f;

  for (int k0 = 0; k0 < HD; k0 += 128) {
#pragma unroll
    for (int r = 0; r < 8; ++r) {
      int idx = r * 256 + tid;
      int row = idx >> 5;
      int c = (idx & 31) * 4;
      *(float4*)&Xs[row][c] = *(const float4*)&x[(size_t)(tok0 + row) * HD + k0 + c];
      *(float4*)&Gs[row][c] = *(const float4*)&gw[(size_t)row * HD + k0 + c];
    }
    __syncthreads();
#pragma unroll 4
    for (int kk = 0; kk < 32; ++kk) {
      float4 xv[4], gv[4];
#pragma unroll
      for (int i = 0; i < 4; ++i) xv[i] = *(float4*)&Xs[th + i * 16][kk * 4];
#pragma unroll
      for (int j = 0; j < 4; ++j) gv[j] = *(float4*)&Gs[te + j * 16][kk * 4];
#pragma unroll
      for (int i = 0; i < 4; ++i)
#pragma unroll
        for (int j = 0; j < 4; ++j) {
          acc[i][j] = fmaf(xv[i].x, gv[j].x, acc[i][j]);
          acc[i][j] = fmaf(xv[i].y, gv[j].y, acc[i][j]);
          acc[i][j] = fmaf(xv[i].z, gv[j].z, acc[i][j]);
          acc[i][j] = fmaf(xv[i].w, gv[j].w, acc[i][j]);
        }
    }
    __syncthreads();
  }
#pragma unroll
  for (int i = 0; i < 4; ++i)
#pragma unroll
    for (int j = 0; j < 4; ++j)
      logits[(size_t)(tok0 + th + i * 16) * NE + te + j * 16] = acc[i][j];
}

// ---------------- top-2 + probs + importance partials ----------------
__global__ __launch_bounds__(256) void topk_kernel(const float* __restrict__ logits,
                                                   int2* __restrict__ e01,
                                                   float2* __restrict__ p01,
                                                   float* __restrict__ imp_part) {
  const int t = blockIdx.x * 256 + threadIdx.x;
  float l[64];
  const float4* lp = (const float4*)(logits + (size_t)t * NE);
#pragma unroll
  for (int i = 0; i < 16; ++i) {
    float4 v = lp[i];
    l[4 * i] = v.x; l[4 * i + 1] = v.y; l[4 * i + 2] = v.z; l[4 * i + 3] = v.w;
  }
  float v1 = -1e30f; int i1 = 0;
#pragma unroll
  for (int j = 0; j < 64; ++j) if (l[j] > v1) { v1 = l[j]; i1 = j; }
  float v2 = -1e30f; int i2 = 0;
#pragma unroll
  for (int j = 0; j < 64; ++j) if (j != i1 && l[j] > v2) { v2 = l[j]; i2 = j; }
  float ex = __expf(v2 - v1);
  float inv2 = 1.f / (1.f + ex);
  e01[t] = make_int2(i1, i2);
  p01[t] = make_float2(inv2, ex * inv2);

  float s = 0.f;
#pragma unroll
  for (int j = 0; j < 64; ++j) s += __expf(l[j] - v1);
  float invs = 1.f / s;
  const int wid = t >> 6;
#pragma unroll
  for (int e = 0; e < 64; ++e) {
    float p = __expf(l[e] - v1) * invs;
#pragma unroll
    for (int off = 32; off; off >>= 1) p += __shfl_xor(p, off);
    if ((threadIdx.x & 63) == 0) imp_part[(size_t)wid * 64 + e] = p;
  }
}

// ---------------- dispatch phase 1: per-tile stable rank + histogram ----------------
__global__ __launch_bounds__(256) void hist_rank_kernel(const int2* __restrict__ e01,
                                                        int* __restrict__ rank_buf,
                                                        int* __restrict__ hist) {
  __shared__ int wave_hist[4][64];
  const int tid = threadIdx.x;
  const int w = tid >> 6, lane = tid & 63;
  const int i = blockIdx.x * 256 + tid;
  int2 ee = e01[i >> 1];
  const int e = (i & 1) ? ee.y : ee.x;
  int rank = 0, cnt = 0;
#pragma unroll
  for (int j = 0; j < 64; ++j) {
    int ej = __shfl(e, j);
    rank += (j < lane) & (ej == e);
    cnt += (ej == lane);
  }
  wave_hist[w][lane] = cnt;
  __syncthreads();
#pragma unroll
  for (int ww = 0; ww < 4; ++ww)
    if (ww < w) rank += wave_hist[ww][e];
  rank_buf[i] = rank;
  if (tid < 64)
    hist[blockIdx.x * 64 + tid] =
        wave_hist[0][tid] + wave_hist[1][tid] + wave_hist[2][tid] + wave_hist[3][tid];
}

// ---------------- dispatch phase 2: per-expert exclusive scan over tiles ----------------
__global__ __launch_bounds__(64) void scan_kernel(const int* __restrict__ hist,
                                                  int* __restrict__ tile_off,
                                                  int* __restrict__ counts) {
  const int e = threadIdx.x;
  int run = 0;
  for (int t = 0; t < NTILE; ++t) {
    int h = hist[t * 64 + e];
    tile_off[t * 64 + e] = run;
    run += h;
  }
  counts[e] = run;
}

// ---------------- dispatch phase 3: place ----------------
__global__ __launch_bounds__(256) void place_kernel(const int2* __restrict__ e01,
                                                    const int* __restrict__ rank_buf,
                                                    const int* __restrict__ tile_off,
                                                    int* __restrict__ slot_of,
                                                    int* __restrict__ slot_token) {
  const int tid = threadIdx.x;
  const int i = blockIdx.x * 256 + tid;
  int2 ee = e01[i >> 1];
  const int e = (i & 1) ? ee.y : ee.x;
  const int pos = tile_off[blockIdx.x * 64 + e] + rank_buf[i];
  const int slot = (pos < CAP) ? (e * CAP + pos) : -1;
  slot_of[i] = slot;
  if (slot >= 0) slot_token[slot] = i;
}

// ---------------- gather tokens -> expert inputs (bf16) ----------------
__global__ __launch_bounds__(128) void gather_kernel(const float* __restrict__ x,
                                                     const int* __restrict__ slot_token,
                                                     __hip_bfloat16* __restrict__ xe) {
  const int slot = blockIdx.x;
  const int tid = threadIdx.x;
  const int i = slot_token[slot];
  __hip_bfloat16* dst = xe + (size_t)slot * HD;
  if (i < 0) {
    bf16x8 z = {};
    *(bf16x8*)(dst + tid * 8) = z;
  } else {
    const int tok = i >> 1;
    const float4* src = (const float4*)(x + (size_t)tok * HD);
    float4 a = src[tid * 2], b = src[tid * 2 + 1];
    bf16x8 o;
    o[0] = f2bf(a.x); o[1] = f2bf(a.y); o[2] = f2bf(a.z); o[3] = f2bf(a.w);
    o[4] = f2bf(b.x); o[5] = f2bf(b.y); o[6] = f2bf(b.z); o[7] = f2bf(b.w);
    *(bf16x8*)(dst + tid * 8) = o;
  }
}

// ---------------- convert expert_w -> bf16 ----------------
__global__ __launch_bounds__(256) void convw_kernel(const float* __restrict__ w,
                                                    __hip_bfloat16* __restrict__ wb) {
  const size_t idx = ((size_t)blockIdx.x * 256 + threadIdx.x) * 8;
  float4 a = *(const float4*)(w + idx);
  float4 b = *(const float4*)(w + idx + 4);
  bf16x8 o;
  o[0] = f2bf(a.x); o[1] = f2bf(a.y); o[2] = f2bf(a.z); o[3] = f2bf(a.w);
  o[4] = f2bf(b.x); o[5] = f2bf(b.y); o[6] = f2bf(b.z); o[7] = f2bf(b.w);
  *(bf16x8*)(wb + idx) = o;
}

// ---------------- grouped expert GEMM ----------------
#define ASYNC16(g, l) __builtin_amdgcn_global_load_lds( \
    (const __attribute__((address_space(1))) void*)(g), \
    (__attribute__((address_space(3))) void*)(l), 16, 0, 0)

__global__ __launch_bounds__(256) void moe_gemm_kernel(const __hip_bfloat16* __restrict__ Xe,
                                                       const __hip_bfloat16* __restrict__ Wb,
                                                       __hip_bfloat16* __restrict__ Eo) {
  __shared__ __hip_bfloat16 As[128 * 32];
  __shared__ __hip_bfloat16 Bs[128 * 32];
  const int e = blockIdx.y;
  const int tm = blockIdx.x >> 3;   // 10 M-tiles
  const int tn = blockIdx.x & 7;    // 8 N-tiles
  const int tid = threadIdx.x;
  const int lane = tid & 63;
  const int w = tid >> 6;
  const int wm = w >> 1, wn = w & 1;

  const __hip_bfloat16* A = Xe + (size_t)e * CAP * HD + (size_t)tm * 128 * HD;
  const __hip_bfloat16* B = Wb + (size_t)e * HD * HD + (size_t)tn * 128 * HD;

  const int srow = tid >> 2;
  const int scol = (tid & 3) * 8;
  const int ldsbase = (tid & 192) * 16;

  f32x4 acc[4][4] = {};
  const int fr = lane & 15;
  const int fq = lane >> 4;

  for (int k0 = 0; k0 < HD; k0 += 32) {
    ASYNC16(A + (size_t)srow * HD + k0 + scol, (char*)As + ldsbase);
    ASYNC16(A + (size_t)(srow + 64) * HD + k0 + scol, (char*)As + 4096 + ldsbase);
    ASYNC16(B + (size_t)srow * HD + k0 + scol, (char*)Bs + ldsbase);
    ASYNC16(B + (size_t)(srow + 64) * HD + k0 + scol, (char*)Bs + 4096 + ldsbase);
    __syncthreads();
    bf16x8 af[4], bb[4];
#pragma unroll
    for (int m = 0; m < 4; ++m)
      af[m] = *(const bf16x8*)(As + (wm * 64 + m * 16 + fr) * 32 + fq * 8);
#pragma unroll
    for (int n = 0; n < 4; ++n)
      bb[n] = *(const bf16x8*)(Bs + (wn * 64 + n * 16 + fr) * 32 + fq * 8);
#pragma unroll
    for (int m = 0; m < 4; ++m)
#pragma unroll
      for (int n = 0; n < 4; ++n)
        acc[m][n] = __builtin_amdgcn_mfma_f32_16x16x32_bf16(af[m], bb[n], acc[m][n], 0, 0, 0);
    __syncthreads();
  }
  __hip_bfloat16* C = Eo + (size_t)e * CAP * HD + (size_t)(tm * 128 + wm * 64) * HD + tn * 128 + wn * 64;
#pragma unroll
  for (int m = 0; m < 4; ++m)
#pragma unroll
    for (int n = 0; n < 4; ++n)
#pragma unroll
      for (int r = 0; r < 4; ++r)
        C[(size_t)(m * 16 + fq * 4 + r) * HD + n * 16 + fr] = __float2bfloat16(acc[m][n][r]);
}

// ---------------- combine ----------------
__global__ __launch_bounds__(256) void combine_kernel(const __hip_bfloat16* __restrict__ eo,
                                                      const int* __restrict__ slot_of,
                                                      const float2* __restrict__ p01,
                                                      float* __restrict__ out) {
  const int t = blockIdx.x;
  const int tid = threadIdx.x;
  const float2 p = p01[t];
  const int s0 = slot_of[2 * t], s1 = slot_of[2 * t + 1];
  float a0 = 0.f, a1 = 0.f, a2 = 0.f, a3 = 0.f;
  if (s0 >= 0) {
    u16x4 v = *(const u16x4*)((const unsigned short*)eo + (size_t)s0 * HD + tid * 4);
    a0 += p.x * bf2f(v[0]); a1 += p.x * bf2f(v[1]);
    a2 += p.x * bf2f(v[2]); a3 += p.x * bf2f(v[3]);
  }
  if (s1 >= 0) {
    u16x4 v = *(const u16x4*)((const unsigned short*)eo + (size_t)s1 * HD + tid * 4);
    a0 += p.y * bf2f(v[0]); a1 += p.y * bf2f(v[1]);
    a2 += p.y * bf2f(v[2]); a3 += p.y * bf2f(v[3]);
  }
  float4 res = make_float4(a0, a1, a2, a3);
  *(float4*)(out + (size_t)t * HD + tid * 4) = res;
}

// ---------------- aux loss ----------------
__global__ __launch_bounds__(64) void aux_kernel(const float* __restrict__ imp_part,
                                                 const int* __restrict__ counts,
                                                 float* __restrict__ out) {
  const int e = threadIdx.x;
  float imp = 0.f;
  for (int w = 0; w < 512; ++w) imp += imp_part[(size_t)w * 64 + e];
  imp *= (1.f / (float)NTOK);
  float usage = (float)counts[e] / (float)NKF;
  float v = usage * imp;
#pragma unroll
  for (int off = 32; off; off >>= 1) v += __shfl_xor(v, off);
  if (e == 0) out[(size_t)NTOK * HD] = fminf(v * (float)NE * 0.01f, 1.0f);
}

extern "C" void kernel_launch(void* const* d_in, const int* in_sizes, int n_in,
                              void* d_out, int out_size, void* d_ws, size_t ws_size,
                              hipStream_t stream) {
  const float* x = (const float*)d_in[0];
  const float* gw = (const float*)d_in[1];
  const float* ew = (const float*)d_in[2];
  float* out = (float*)d_out;

  char* p = (char*)d_ws;
  float* logits = (float*)p;            p += (size_t)NTOK * NE * 4;
  int2* e01 = (int2*)p;                 p += (size_t)NTOK * 8;
  float2* p01 = (float2*)p;             p += (size_t)NTOK * 8;
  int* slot_of = (int*)p;               p += (size_t)NKF * 4;
  int* slot_token = (int*)p;            p += (size_t)NSLOT * 4;
  int* counts = (int*)p;                p += 256;
  float* imp_part = (float*)p;          p += (size_t)512 * 64 * 4;
  int* rank_buf = (int*)p;              p += (size_t)NKF * 4;
  int* hist = (int*)p;                  p += (size_t)NTILE * 64 * 4;
  int* tile_off = (int*)p;              p += (size_t)NTILE * 64 * 4;
  __hip_bfloat16* Wb = (__hip_bfloat16*)p;  p += (size_t)NE * HD * HD * 2;
  __hip_bfloat16* Xe = (__hip_bfloat16*)p;  p += (size_t)NSLOT * HD * 2;
  __hip_bfloat16* Eo = (__hip_bfloat16*)p;  p += (size_t)NSLOT * HD * 2;

  hipMemsetAsync(slot_token, 0xFF, (size_t)NSLOT * 4, stream);

  convw_kernel<<<32768, 256, 0, stream>>>(ew, Wb);
  gating_kernel<<<NTOK / 64, 256, 0, stream>>>(x, gw, logits);
  topk_kernel<<<NTOK / 256, 256, 0, stream>>>(logits, e01, p01, imp_part);
  hist_rank_kernel<<<NTILE, 256, 0, stream>>>(e01, rank_buf, hist);
  scan_kernel<<<1, 64, 0, stream>>>(hist, tile_off, counts);
  place_kernel<<<NTILE, 256, 0, stream>>>(e01, rank_buf, tile_off, slot_of, slot_token);
  gather_kernel<<<NSLOT, 128, 0, stream>>>(x, slot_token, Xe);
  moe_gemm_kernel<<<dim3(80, 64), 256, 0, stream>>>(Xe, Wb, Eo);
  combine_kernel<<<NTOK, 256, 0, stream>>>(Eo, slot_of, p01, out);
  aux_kernel<<<1, 64, 0, stream>>>(imp_part, counts, out);
}

// Round 5
// 501.200 us; speedup vs baseline: 1.6949x; 1.1691x over previous
//
#include <hip/hip_runtime.h>
#include <hip/hip_bf16.h>

#define NTOK 32768
#define NE 64
#define HD 1024
#define CAP 1280
#define NKF (NTOK*2)      // 65536 flat (token,k)
#define NSLOT (NE*CAP)    // 81920
#define NTILE 256         // dispatch tiles of 256 items

typedef __attribute__((ext_vector_type(8))) short bf16x8;
typedef __attribute__((ext_vector_type(4))) float f32x4;
typedef __attribute__((ext_vector_type(4))) unsigned short u16x4;

__device__ __forceinline__ short f2bf(float f) {
  union { __hip_bfloat16 b; short s; } u;
  u.b = __float2bfloat16(f);
  return u.s;
}
__device__ __forceinline__ float bf2f(unsigned short h) {
  return __uint_as_float(((unsigned)h) << 16);
}

// ---------------- gating: logits[N,64] = x @ gw^T (fp32) ----------------
__global__ __launch_bounds__(256) void gating_kernel(const float* __restrict__ x,
                                                     const float* __restrict__ gw,
                                                     float* __restrict__ logits) {
  __shared__ float Xs[64][132];
  __shared__ float Gs[64][132];
  const int tid = threadIdx.x;
  const int tok0 = blockIdx.x * 64;
  const int th = tid >> 4;   // token sub-row 0..15
  const int te = tid & 15;   // expert sub-col 0..15
  float acc[4][4];
#pragma unroll
  for (int i = 0; i < 4; ++i)
#pragma unroll
    for (int j = 0; j < 4; ++j) acc[i][j] = 0.f;

  for (int k0 = 0; k0 < HD; k0 += 128) {
#pragma unroll
    for (int r = 0; r < 8; ++r) {
      int idx = r * 256 + tid;
      int row = idx >> 5;
      int c = (idx & 31) * 4;
      *(float4*)&Xs[row][c] = *(const float4*)&x[(size_t)(tok0 + row) * HD + k0 + c];
      *(float4*)&Gs[row][c] = *(const float4*)&gw[(size_t)row * HD + k0 + c];
    }
    __syncthreads();
#pragma unroll 4
    for (int kk = 0; kk < 32; ++kk) {
      float4 xv[4], gv[4];
#pragma unroll
      for (int i = 0; i < 4; ++i) xv[i] = *(float4*)&Xs[th + i * 16][kk * 4];
#pragma unroll
      for (int j = 0; j < 4; ++j) gv[j] = *(float4*)&Gs[te + j * 16][kk * 4];
#pragma unroll
      for (int i = 0; i < 4; ++i)
#pragma unroll
        for (int j = 0; j < 4; ++j) {
          acc[i][j] = fmaf(xv[i].x, gv[j].x, acc[i][j]);
          acc[i][j] = fmaf(xv[i].y, gv[j].y, acc[i][j]);
          acc[i][j] = fmaf(xv[i].z, gv[j].z, acc[i][j]);
          acc[i][j] = fmaf(xv[i].w, gv[j].w, acc[i][j]);
        }
    }
    __syncthreads();
  }
#pragma unroll
  for (int i = 0; i < 4; ++i)
#pragma unroll
    for (int j = 0; j < 4; ++j)
      logits[(size_t)(tok0 + th + i * 16) * NE + te + j * 16] = acc[i][j];
}

// ---------------- top-2 + probs + importance partials ----------------
__global__ __launch_bounds__(256) void topk_kernel(const float* __restrict__ logits,
                                                   int2* __restrict__ e01,
                                                   float2* __restrict__ p01,
                                                   float* __restrict__ imp_part) {
  const int t = blockIdx.x * 256 + threadIdx.x;
  float l[64];
  const float4* lp = (const float4*)(logits + (size_t)t * NE);
#pragma unroll
  for (int i = 0; i < 16; ++i) {
    float4 v = lp[i];
    l[4 * i] = v.x; l[4 * i + 1] = v.y; l[4 * i + 2] = v.z; l[4 * i + 3] = v.w;
  }
  float v1 = -1e30f; int i1 = 0;
#pragma unroll
  for (int j = 0; j < 64; ++j) if (l[j] > v1) { v1 = l[j]; i1 = j; }
  float v2 = -1e30f; int i2 = 0;
#pragma unroll
  for (int j = 0; j < 64; ++j) if (j != i1 && l[j] > v2) { v2 = l[j]; i2 = j; }
  float ex = __expf(v2 - v1);
  float inv2 = 1.f / (1.f + ex);
  e01[t] = make_int2(i1, i2);
  p01[t] = make_float2(inv2, ex * inv2);

  float s = 0.f;
#pragma unroll
  for (int j = 0; j < 64; ++j) s += __expf(l[j] - v1);
  float invs = 1.f / s;
  const int wid = t >> 6;
#pragma unroll
  for (int e = 0; e < 64; ++e) {
    float p = __expf(l[e] - v1) * invs;
#pragma unroll
    for (int off = 32; off; off >>= 1) p += __shfl_xor(p, off);
    if ((threadIdx.x & 63) == 0) imp_part[(size_t)wid * 64 + e] = p;
  }
}

// ---------------- dispatch phase 1: per-tile stable rank + histogram ----------------
__global__ __launch_bounds__(256) void hist_rank_kernel(const int2* __restrict__ e01,
                                                        int* __restrict__ rank_buf,
                                                        int* __restrict__ hist) {
  __shared__ int wave_hist[4][64];
  const int tid = threadIdx.x;
  const int w = tid >> 6, lane = tid & 63;
  const int i = blockIdx.x * 256 + tid;
  int2 ee = e01[i >> 1];
  const int e = (i & 1) ? ee.y : ee.x;
  int rank = 0, cnt = 0;
#pragma unroll
  for (int j = 0; j < 64; ++j) {
    int ej = __shfl(e, j);
    rank += (j < lane) & (ej == e);
    cnt += (ej == lane);
  }
  wave_hist[w][lane] = cnt;
  __syncthreads();
#pragma unroll
  for (int ww = 0; ww < 4; ++ww)
    if (ww < w) rank += wave_hist[ww][e];
  rank_buf[i] = rank;
  if (tid < 64)
    hist[blockIdx.x * 64 + tid] =
        wave_hist[0][tid] + wave_hist[1][tid] + wave_hist[2][tid] + wave_hist[3][tid];
}

// ---------------- dispatch phase 2: per-expert exclusive scan over tiles ----------------
__global__ __launch_bounds__(64) void scan_kernel(const int* __restrict__ hist,
                                                  int* __restrict__ tile_off,
                                                  int* __restrict__ counts) {
  const int e = threadIdx.x;
  int run = 0;
  for (int t = 0; t < NTILE; ++t) {
    int h = hist[t * 64 + e];
    tile_off[t * 64 + e] = run;
    run += h;
  }
  counts[e] = run;
}

// ---------------- dispatch phase 3: place ----------------
__global__ __launch_bounds__(256) void place_kernel(const int2* __restrict__ e01,
                                                    const int* __restrict__ rank_buf,
                                                    const int* __restrict__ tile_off,
                                                    int* __restrict__ slot_of,
                                                    int* __restrict__ slot_token) {
  const int tid = threadIdx.x;
  const int i = blockIdx.x * 256 + tid;
  int2 ee = e01[i >> 1];
  const int e = (i & 1) ? ee.y : ee.x;
  const int pos = tile_off[blockIdx.x * 64 + e] + rank_buf[i];
  const int slot = (pos < CAP) ? (e * CAP + pos) : -1;
  slot_of[i] = slot;
  if (slot >= 0) slot_token[slot] = i;
}

// ---------------- gather tokens -> expert inputs (bf16) ----------------
__global__ __launch_bounds__(128) void gather_kernel(const float* __restrict__ x,
                                                     const int* __restrict__ slot_token,
                                                     __hip_bfloat16* __restrict__ xe) {
  const int slot = blockIdx.x;
  const int tid = threadIdx.x;
  const int i = slot_token[slot];
  __hip_bfloat16* dst = xe + (size_t)slot * HD;
  if (i < 0) {
    bf16x8 z = {};
    *(bf16x8*)(dst + tid * 8) = z;
  } else {
    const int tok = i >> 1;
    const float4* src = (const float4*)(x + (size_t)tok * HD);
    float4 a = src[tid * 2], b = src[tid * 2 + 1];
    bf16x8 o;
    o[0] = f2bf(a.x); o[1] = f2bf(a.y); o[2] = f2bf(a.z); o[3] = f2bf(a.w);
    o[4] = f2bf(b.x); o[5] = f2bf(b.y); o[6] = f2bf(b.z); o[7] = f2bf(b.w);
    *(bf16x8*)(dst + tid * 8) = o;
  }
}

// ---------------- convert expert_w -> bf16 ----------------
__global__ __launch_bounds__(256) void convw_kernel(const float* __restrict__ w,
                                                    __hip_bfloat16* __restrict__ wb) {
  const size_t idx = ((size_t)blockIdx.x * 256 + threadIdx.x) * 8;
  float4 a = *(const float4*)(w + idx);
  float4 b = *(const float4*)(w + idx + 4);
  bf16x8 o;
  o[0] = f2bf(a.x); o[1] = f2bf(a.y); o[2] = f2bf(a.z); o[3] = f2bf(a.w);
  o[4] = f2bf(b.x); o[5] = f2bf(b.y); o[6] = f2bf(b.z); o[7] = f2bf(b.w);
  *(bf16x8*)(wb + idx) = o;
}

// ---------------- grouped expert GEMM: 256x256 tile, BK=64, 8-wave 8-phase ----------------
#define ASYNC16(g, l) __builtin_amdgcn_global_load_lds( \
    (const __attribute__((address_space(1))) void*)(g), \
    (__attribute__((address_space(3))) void*)(l), 16, 0, 0)

// stage one 256x32 k-slice (2 rounds of 128 rows); LDS dest linear, source inverse-swizzled
#define STAGE(P, abase, buf, ks, kcol) do {                                     \
    const __hip_bfloat16* _g = (P) + (size_t)srow * HD + (kcol) + (ks) * 32 + sw8; \
    const int _d = ((abase) + (buf) * 16384 + (ks) * 8192 + wuni) * 2;          \
    ASYNC16(_g, (char*)lds + _d);                                               \
    ASYNC16(_g + (size_t)128 * HD, (char*)lds + _d + 8192);                     \
  } while (0)

#define LDA(dst, buf, ks, mi) \
  dst = *(const bf16x8*)(lds + (buf) * 16384 + (ks) * 8192 + (wm * 128 + (mi) * 16 + fr) * 32 + rsw)
#define LDB(dst, buf, ks, ni) \
  dst = *(const bf16x8*)(lds + 32768 + (buf) * 16384 + (ks) * 8192 + (wn * 64 + (ni) * 16 + fr) * 32 + rsw)

#define MFMA_HALF(h)                                                            \
  _Pragma("unroll")                                                             \
  for (int mm = 0; mm < 4; ++mm)                                                \
    _Pragma("unroll")                                                           \
    for (int nn = 0; nn < 4; ++nn)                                              \
      acc[(h) * 4 + mm][nn] =                                                   \
          __builtin_amdgcn_mfma_f32_16x16x32_bf16(av[mm], bv[nn], acc[(h) * 4 + mm][nn], 0, 0, 0)

#define BARX() do { asm volatile("" ::: "memory"); __builtin_amdgcn_s_barrier(); asm volatile("" ::: "memory"); } while (0)

__global__ __launch_bounds__(512, 2) void moe_gemm_kernel(const __hip_bfloat16* __restrict__ Xe,
                                                          const __hip_bfloat16* __restrict__ Wb,
                                                          __hip_bfloat16* __restrict__ Eo) {
  __shared__ __hip_bfloat16 lds[65536];  // A: [2buf][2ks][256][32] @0 ; B: same @32768

  // bijective XCD swizzle: 1280 blocks, 8 XCDs, 160 contiguous per XCD
  const int bid = blockIdx.x;
  const int swz = (bid & 7) * 160 + (bid >> 3);
  const int e = swz / 20;
  const int t20 = swz - e * 20;
  const int tm = t20 >> 2, tn = t20 & 3;

  const int tid = threadIdx.x;
  const int lane = tid & 63;
  const int w = tid >> 6;            // 0..7
  const int wm = w >> 2, wn = w & 3; // 2 x 4 wave grid; per-wave 128x64 output

  const __hip_bfloat16* A = Xe + (size_t)e * CAP * HD + (size_t)(tm * 256) * HD;
  const __hip_bfloat16* B = Wb + (size_t)e * HD * HD + (size_t)(tn * 256) * HD;

  const int srow = tid >> 2;                                  // staging row within round
  const int sw8 = ((tid & 3) ^ ((tid >> 3) & 3)) * 8;         // inverse-swizzled source col
  const int wuni = w * 512;                                   // wave-uniform LDS elems

  const int fr = lane & 15;
  const int fq = lane >> 4;
  const int rsw = (fq ^ ((fr >> 1) & 3)) * 8;                 // swizzled read col elems

  f32x4 acc[8][4] = {};

  // prologue: all 4 units of K-tile 0 into buf 0; keep V2/V3 in flight
  STAGE(A, 0, 0, 0, 0);
  STAGE(B, 32768, 0, 0, 0);
  STAGE(A, 0, 0, 1, 0);
  STAGE(B, 32768, 0, 1, 0);
  asm volatile("s_waitcnt vmcnt(4)" ::: "memory");
  BARX();

#pragma unroll 2
  for (int t = 0; t < 16; ++t) {
    const int cur = t & 1, nxt = cur ^ 1;
    const int kc = (t + 1) * 64;
    const bool hn = (t < 15);
    bf16x8 av[4], bv[4];

    // ---- phase 0: ks0, m-half 0 (B frags held for phase 1) ----
    LDB(bv[0], cur, 0, 0); LDB(bv[1], cur, 0, 1); LDB(bv[2], cur, 0, 2); LDB(bv[3], cur, 0, 3);
    LDA(av[0], cur, 0, 0); LDA(av[1], cur, 0, 1); LDA(av[2], cur, 0, 2); LDA(av[3], cur, 0, 3);
    if (hn) STAGE(A, 0, nxt, 0, kc);
    BARX();
    __builtin_amdgcn_s_setprio(1);
    MFMA_HALF(0);
    __builtin_amdgcn_s_setprio(0);
    BARX();

    // ---- phase 1: ks0, m-half 1 ----
    LDA(av[0], cur, 0, 4); LDA(av[1], cur, 0, 5); LDA(av[2], cur, 0, 6); LDA(av[3], cur, 0, 7);
    if (hn) {
      STAGE(B, 32768, nxt, 0, kc);
      asm volatile("s_waitcnt vmcnt(4)" ::: "memory");  // V2,V3(t) complete for phases 2,3
    } else {
      asm volatile("s_waitcnt vmcnt(0)" ::: "memory");  // final tile: drain V2,V3(15)
    }
    BARX();
    __builtin_amdgcn_s_setprio(1);
    MFMA_HALF(1);
    __builtin_amdgcn_s_setprio(0);
    BARX();

    // ---- phase 2: ks1, m-half 0 ----
    LDB(bv[0], cur, 1, 0); LDB(bv[1], cur, 1, 1); LDB(bv[2], cur, 1, 2); LDB(bv[3], cur, 1, 3);
    LDA(av[0], cur, 1, 0); LDA(av[1], cur, 1, 1); LDA(av[2], cur, 1, 2); LDA(av[3], cur, 1, 3);
    if (hn) STAGE(A, 0, nxt, 1, kc);
    BARX();
    __builtin_amdgcn_s_setprio(1);
    MFMA_HALF(0);
    __builtin_amdgcn_s_setprio(0);
    BARX();

    // ---- phase 3: ks1, m-half 1 ----
    LDA(av[0], cur, 1, 4); LDA(av[1], cur, 1, 5); LDA(av[2], cur, 1, 6); LDA(av[3], cur, 1, 7);
    if (hn) {
      STAGE(B, 32768, nxt, 1, kc);
      asm volatile("s_waitcnt vmcnt(4)" ::: "memory");  // V0,V1(t+1) complete for next ph0/1
    }
    BARX();
    __builtin_amdgcn_s_setprio(1);
    MFMA_HALF(1);
    __builtin_amdgcn_s_setprio(0);
    BARX();
  }

  __hip_bfloat16* C = Eo + (size_t)e * CAP * HD +
                      (size_t)(tm * 256 + wm * 128) * HD + tn * 256 + wn * 64;
#pragma unroll
  for (int m = 0; m < 8; ++m)
#pragma unroll
    for (int n = 0; n < 4; ++n)
#pragma unroll
      for (int r = 0; r < 4; ++r)
        C[(size_t)(m * 16 + fq * 4 + r) * HD + n * 16 + fr] = __float2bfloat16(acc[m][n][r]);
}

// ---------------- combine ----------------
__global__ __launch_bounds__(256) void combine_kernel(const __hip_bfloat16* __restrict__ eo,
                                                      const int* __restrict__ slot_of,
                                                      const float2* __restrict__ p01,
                                                      float* __restrict__ out) {
  const int t = blockIdx.x;
  const int tid = threadIdx.x;
  const float2 p = p01[t];
  const int s0 = slot_of[2 * t], s1 = slot_of[2 * t + 1];
  float a0 = 0.f, a1 = 0.f, a2 = 0.f, a3 = 0.f;
  if (s0 >= 0) {
    u16x4 v = *(const u16x4*)((const unsigned short*)eo + (size_t)s0 * HD + tid * 4);
    a0 += p.x * bf2f(v[0]); a1 += p.x * bf2f(v[1]);
    a2 += p.x * bf2f(v[2]); a3 += p.x * bf2f(v[3]);
  }
  if (s1 >= 0) {
    u16x4 v = *(const u16x4*)((const unsigned short*)eo + (size_t)s1 * HD + tid * 4);
    a0 += p.y * bf2f(v[0]); a1 += p.y * bf2f(v[1]);
    a2 += p.y * bf2f(v[2]); a3 += p.y * bf2f(v[3]);
  }
  float4 res = make_float4(a0, a1, a2, a3);
  *(float4*)(out + (size_t)t * HD + tid * 4) = res;
}

// ---------------- aux loss ----------------
__global__ __launch_bounds__(64) void aux_kernel(const float* __restrict__ imp_part,
                                                 const int* __restrict__ counts,
                                                 float* __restrict__ out) {
  const int e = threadIdx.x;
  float imp = 0.f;
  for (int w = 0; w < 512; ++w) imp += imp_part[(size_t)w * 64 + e];
  imp *= (1.f / (float)NTOK);
  float usage = (float)counts[e] / (float)NKF;
  float v = usage * imp;
#pragma unroll
  for (int off = 32; off; off >>= 1) v += __shfl_xor(v, off);
  if (e == 0) out[(size_t)NTOK * HD] = fminf(v * (float)NE * 0.01f, 1.0f);
}

extern "C" void kernel_launch(void* const* d_in, const int* in_sizes, int n_in,
                              void* d_out, int out_size, void* d_ws, size_t ws_size,
                              hipStream_t stream) {
  const float* x = (const float*)d_in[0];
  const float* gw = (const float*)d_in[1];
  const float* ew = (const float*)d_in[2];
  float* out = (float*)d_out;

  char* p = (char*)d_ws;
  float* logits = (float*)p;            p += (size_t)NTOK * NE * 4;
  int2* e01 = (int2*)p;                 p += (size_t)NTOK * 8;
  float2* p01 = (float2*)p;             p += (size_t)NTOK * 8;
  int* slot_of = (int*)p;               p += (size_t)NKF * 4;
  int* slot_token = (int*)p;            p += (size_t)NSLOT * 4;
  int* counts = (int*)p;                p += 256;
  float* imp_part = (float*)p;          p += (size_t)512 * 64 * 4;
  int* rank_buf = (int*)p;              p += (size_t)NKF * 4;
  int* hist = (int*)p;                  p += (size_t)NTILE * 64 * 4;
  int* tile_off = (int*)p;              p += (size_t)NTILE * 64 * 4;
  __hip_bfloat16* Wb = (__hip_bfloat16*)p;  p += (size_t)NE * HD * HD * 2;
  __hip_bfloat16* Xe = (__hip_bfloat16*)p;  p += (size_t)NSLOT * HD * 2;
  __hip_bfloat16* Eo = (__hip_bfloat16*)p;  p += (size_t)NSLOT * HD * 2;

  hipMemsetAsync(slot_token, 0xFF, (size_t)NSLOT * 4, stream);

  convw_kernel<<<32768, 256, 0, stream>>>(ew, Wb);
  gating_kernel<<<NTOK / 64, 256, 0, stream>>>(x, gw, logits);
  topk_kernel<<<NTOK / 256, 256, 0, stream>>>(logits, e01, p01, imp_part);
  hist_rank_kernel<<<NTILE, 256, 0, stream>>>(e01, rank_buf, hist);
  scan_kernel<<<1, 64, 0, stream>>>(hist, tile_off, counts);
  place_kernel<<<NTILE, 256, 0, stream>>>(e01, rank_buf, tile_off, slot_of, slot_token);
  gather_kernel<<<NSLOT, 128, 0, stream>>>(x, slot_token, Xe);
  moe_gemm_kernel<<<dim3(1280), 512, 0, stream>>>(Xe, Wb, Eo);
  combine_kernel<<<NTOK, 256, 0, stream>>>(Eo, slot_of, p01, out);
  aux_kernel<<<1, 64, 0, stream>>>(imp_part, counts, out);
}

// Round 6
// 442.245 us; speedup vs baseline: 1.9209x; 1.1333x over previous
//
#include <hip/hip_runtime.h>
#include <hip/hip_bf16.h>

#define NTOK 32768
#define NE 64
#define HD 1024
#define CAP 1280
#define NKF (NTOK*2)      // 65536 flat (token,k)
#define NSLOT (NE*CAP)    // 81920
#define NTILE 256         // dispatch tiles of 256 items

typedef __attribute__((ext_vector_type(8))) short bf16x8;
typedef __attribute__((ext_vector_type(4))) short bf16x4;
typedef __attribute__((ext_vector_type(4))) float f32x4;
typedef __attribute__((ext_vector_type(4))) unsigned short u16x4;

__device__ __forceinline__ short f2bf(float f) {
  union { __hip_bfloat16 b; short s; } u;
  u.b = __float2bfloat16(f);
  return u.s;
}
__device__ __forceinline__ float bf2f(unsigned short h) {
  return __uint_as_float(((unsigned)h) << 16);
}

// ---------------- gating: logits[N,64] = x @ gw^T (fp32) + emit compact bf16 x ----------------
__global__ __launch_bounds__(256) void gating_kernel(const float* __restrict__ x,
                                                     const float* __restrict__ gw,
                                                     float* __restrict__ logits,
                                                     __hip_bfloat16* __restrict__ xb) {
  __shared__ float Xs[64][132];
  __shared__ float Gs[64][132];
  const int tid = threadIdx.x;
  const int tok0 = blockIdx.x * 64;
  const int th = tid >> 4;   // token sub-row 0..15
  const int te = tid & 15;   // expert sub-col 0..15
  float acc[4][4];
#pragma unroll
  for (int i = 0; i < 4; ++i)
#pragma unroll
    for (int j = 0; j < 4; ++j) acc[i][j] = 0.f;

  for (int k0 = 0; k0 < HD; k0 += 128) {
#pragma unroll
    for (int r = 0; r < 8; ++r) {
      int idx = r * 256 + tid;
      int row = idx >> 5;
      int c = (idx & 31) * 4;
      float4 xv4 = *(const float4*)&x[(size_t)(tok0 + row) * HD + k0 + c];
      *(float4*)&Xs[row][c] = xv4;
      bf16x4 o;
      o[0] = f2bf(xv4.x); o[1] = f2bf(xv4.y); o[2] = f2bf(xv4.z); o[3] = f2bf(xv4.w);
      *(bf16x4*)&xb[(size_t)(tok0 + row) * HD + k0 + c] = o;
      *(float4*)&Gs[row][c] = *(const float4*)&gw[(size_t)row * HD + k0 + c];
    }
    __syncthreads();
#pragma unroll 4
    for (int kk = 0; kk < 32; ++kk) {
      float4 xv[4], gv[4];
#pragma unroll
      for (int i = 0; i < 4; ++i) xv[i] = *(float4*)&Xs[th + i * 16][kk * 4];
#pragma unroll
      for (int j = 0; j < 4; ++j) gv[j] = *(float4*)&Gs[te + j * 16][kk * 4];
#pragma unroll
      for (int i = 0; i < 4; ++i)
#pragma unroll
        for (int j = 0; j < 4; ++j) {
          acc[i][j] = fmaf(xv[i].x, gv[j].x, acc[i][j]);
          acc[i][j] = fmaf(xv[i].y, gv[j].y, acc[i][j]);
          acc[i][j] = fmaf(xv[i].z, gv[j].z, acc[i][j]);
          acc[i][j] = fmaf(xv[i].w, gv[j].w, acc[i][j]);
        }
    }
    __syncthreads();
  }
#pragma unroll
  for (int i = 0; i < 4; ++i)
#pragma unroll
    for (int j = 0; j < 4; ++j)
      logits[(size_t)(tok0 + th + i * 16) * NE + te + j * 16] = acc[i][j];
}

// ---------------- top-2 + probs + importance partials ----------------
__global__ __launch_bounds__(256) void topk_kernel(const float* __restrict__ logits,
                                                   int2* __restrict__ e01,
                                                   float2* __restrict__ p01,
                                                   float* __restrict__ imp_part) {
  const int t = blockIdx.x * 256 + threadIdx.x;
  float l[64];
  const float4* lp = (const float4*)(logits + (size_t)t * NE);
#pragma unroll
  for (int i = 0; i < 16; ++i) {
    float4 v = lp[i];
    l[4 * i] = v.x; l[4 * i + 1] = v.y; l[4 * i + 2] = v.z; l[4 * i + 3] = v.w;
  }
  float v1 = -1e30f; int i1 = 0;
#pragma unroll
  for (int j = 0; j < 64; ++j) if (l[j] > v1) { v1 = l[j]; i1 = j; }
  float v2 = -1e30f; int i2 = 0;
#pragma unroll
  for (int j = 0; j < 64; ++j) if (j != i1 && l[j] > v2) { v2 = l[j]; i2 = j; }
  float ex = __expf(v2 - v1);
  float inv2 = 1.f / (1.f + ex);
  e01[t] = make_int2(i1, i2);
  p01[t] = make_float2(inv2, ex * inv2);

  float s = 0.f;
#pragma unroll
  for (int j = 0; j < 64; ++j) s += __expf(l[j] - v1);
  float invs = 1.f / s;
  const int wid = t >> 6;
#pragma unroll
  for (int e = 0; e < 64; ++e) {
    float p = __expf(l[e] - v1) * invs;
#pragma unroll
    for (int off = 32; off; off >>= 1) p += __shfl_xor(p, off);
    if ((threadIdx.x & 63) == 0) imp_part[(size_t)wid * 64 + e] = p;
  }
}

// ---------------- dispatch phase 1: per-tile stable rank + histogram ----------------
__global__ __launch_bounds__(256) void hist_rank_kernel(const int2* __restrict__ e01,
                                                        int* __restrict__ rank_buf,
                                                        int* __restrict__ hist) {
  __shared__ int wave_hist[4][64];
  const int tid = threadIdx.x;
  const int w = tid >> 6, lane = tid & 63;
  const int i = blockIdx.x * 256 + tid;
  int2 ee = e01[i >> 1];
  const int e = (i & 1) ? ee.y : ee.x;
  int rank = 0, cnt = 0;
#pragma unroll
  for (int j = 0; j < 64; ++j) {
    int ej = __shfl(e, j);
    rank += (j < lane) & (ej == e);
    cnt += (ej == lane);
  }
  wave_hist[w][lane] = cnt;
  __syncthreads();
#pragma unroll
  for (int ww = 0; ww < 4; ++ww)
    if (ww < w) rank += wave_hist[ww][e];
  rank_buf[i] = rank;
  if (tid < 64)
    hist[blockIdx.x * 64 + tid] =
        wave_hist[0][tid] + wave_hist[1][tid] + wave_hist[2][tid] + wave_hist[3][tid];
}

// ---------------- dispatch phase 2: per-expert exclusive scan over tiles ----------------
__global__ __launch_bounds__(64) void scan_kernel(const int* __restrict__ hist,
                                                  int* __restrict__ tile_off,
                                                  int* __restrict__ counts) {
  const int e = threadIdx.x;
  int run = 0;
  for (int t = 0; t < NTILE; ++t) {
    int h = hist[t * 64 + e];
    tile_off[t * 64 + e] = run;
    run += h;
  }
  counts[e] = run;
}

// ---------------- dispatch phase 3: place ----------------
__global__ __launch_bounds__(256) void place_kernel(const int2* __restrict__ e01,
                                                    const int* __restrict__ rank_buf,
                                                    const int* __restrict__ tile_off,
                                                    int* __restrict__ slot_of,
                                                    int* __restrict__ slot_token) {
  const int tid = threadIdx.x;
  const int i = blockIdx.x * 256 + tid;
  int2 ee = e01[i >> 1];
  const int e = (i & 1) ? ee.y : ee.x;
  const int pos = tile_off[blockIdx.x * 64 + e] + rank_buf[i];
  const int slot = (pos < CAP) ? (e * CAP + pos) : -1;
  slot_of[i] = slot;
  if (slot >= 0) slot_token[slot] = i;
}

// ---------------- convert expert_w -> bf16 ----------------
__global__ __launch_bounds__(256) void convw_kernel(const float* __restrict__ w,
                                                    __hip_bfloat16* __restrict__ wb) {
  const size_t idx = ((size_t)blockIdx.x * 256 + threadIdx.x) * 8;
  float4 a = *(const float4*)(w + idx);
  float4 b = *(const float4*)(w + idx + 4);
  bf16x8 o;
  o[0] = f2bf(a.x); o[1] = f2bf(a.y); o[2] = f2bf(a.z); o[3] = f2bf(a.w);
  o[4] = f2bf(b.x); o[5] = f2bf(b.y); o[6] = f2bf(b.z); o[7] = f2bf(b.w);
  *(bf16x8*)(wb + idx) = o;
}

// ---------------- grouped expert GEMM: 256x256 tile, BK=64, 8-wave, fused A-gather ----------------
#define ASYNC16(g, l) __builtin_amdgcn_global_load_lds( \
    (const __attribute__((address_space(1))) void*)(g), \
    (__attribute__((address_space(3))) void*)(l), 16, 0, 0)

// A: per-thread gathered row pointers (token rows of xb, or zero page)
#define STAGE_A(buf, ks, kcol) do {                                             \
    const int _d = ((buf) * 16384 + (ks) * 8192 + wuni) * 2;                    \
    ASYNC16(arow0 + (kcol) + (ks) * 32 + sw8, (char*)lds + _d);                 \
    ASYNC16(arow1 + (kcol) + (ks) * 32 + sw8, (char*)lds + _d + 8192);          \
  } while (0)

// B: linear panel from Wb
#define STAGE_B(buf, ks, kcol) do {                                             \
    const __hip_bfloat16* _g = B + (size_t)srow * HD + (kcol) + (ks) * 32 + sw8; \
    const int _d = (32768 + (buf) * 16384 + (ks) * 8192 + wuni) * 2;            \
    ASYNC16(_g, (char*)lds + _d);                                               \
    ASYNC16(_g + (size_t)128 * HD, (char*)lds + _d + 8192);                     \
  } while (0)

#define LDA(dst, buf, ks, mi) \
  dst = *(const bf16x8*)(lds + (buf) * 16384 + (ks) * 8192 + (wm * 128 + (mi) * 16 + fr) * 32 + rsw)
#define LDB(dst, buf, ks, ni) \
  dst = *(const bf16x8*)(lds + 32768 + (buf) * 16384 + (ks) * 8192 + (wn * 64 + (ni) * 16 + fr) * 32 + rsw)

#define MFMA_HALF(h)                                                            \
  _Pragma("unroll")                                                             \
  for (int mm = 0; mm < 4; ++mm)                                                \
    _Pragma("unroll")                                                           \
    for (int nn = 0; nn < 4; ++nn)                                              \
      acc[(h) * 4 + mm][nn] =                                                   \
          __builtin_amdgcn_mfma_f32_16x16x32_bf16(av[mm], bv[nn], acc[(h) * 4 + mm][nn], 0, 0, 0)

#define BARX() do { asm volatile("" ::: "memory"); __builtin_amdgcn_s_barrier(); asm volatile("" ::: "memory"); } while (0)

__global__ __launch_bounds__(512, 2) void moe_gemm_kernel(const __hip_bfloat16* __restrict__ xb,
                                                          const int* __restrict__ slot_token,
                                                          const __hip_bfloat16* __restrict__ Wb,
                                                          const __hip_bfloat16* __restrict__ zp,
                                                          __hip_bfloat16* __restrict__ Eo) {
  __shared__ __hip_bfloat16 lds[65536];  // A: [2buf][2ks][256][32] @0 ; B: same @32768

  // bijective XCD swizzle: 1280 blocks, 8 XCDs, 160 contiguous per XCD
  const int bid = blockIdx.x;
  const int swz = (bid & 7) * 160 + (bid >> 3);
  const int e = swz / 20;
  const int t20 = swz - e * 20;
  const int tm = t20 >> 2, tn = t20 & 3;

  const int tid = threadIdx.x;
  const int lane = tid & 63;
  const int w = tid >> 6;            // 0..7
  const int wm = w >> 2, wn = w & 3; // 2 x 4 wave grid; per-wave 128x64 output

  const __hip_bfloat16* B = Wb + (size_t)e * HD * HD + (size_t)(tn * 256) * HD;

  const int srow = tid >> 2;                                  // staging row within round
  const int sw8 = ((tid & 3) ^ ((tid >> 3) & 3)) * 8;         // inverse-swizzled source col
  const int wuni = w * 512;                                   // wave-uniform LDS elems

  // fused A-gather: resolve this thread's two staging-row pointers once
  const int slotbase = e * CAP + tm * 256;
  const int i0 = slot_token[slotbase + srow];
  const int i1 = slot_token[slotbase + 128 + srow];
  const __hip_bfloat16* arow0 = (i0 >= 0) ? xb + (size_t)(i0 >> 1) * HD : zp;
  const __hip_bfloat16* arow1 = (i1 >= 0) ? xb + (size_t)(i1 >> 1) * HD : zp;

  const int fr = lane & 15;
  const int fq = lane >> 4;
  const int rsw = (fq ^ ((fr >> 1) & 3)) * 8;                 // swizzled read col elems

  f32x4 acc[8][4] = {};

  // prologue: all 4 units of K-tile 0 into buf 0; keep V2/V3 in flight
  STAGE_A(0, 0, 0);
  STAGE_B(0, 0, 0);
  STAGE_A(0, 1, 0);
  STAGE_B(0, 1, 0);
  asm volatile("s_waitcnt vmcnt(4)" ::: "memory");
  BARX();

#pragma unroll 2
  for (int t = 0; t < 16; ++t) {
    const int cur = t & 1, nxt = cur ^ 1;
    const int kc = (t + 1) * 64;
    const bool hn = (t < 15);
    bf16x8 av[4], bv[4];

    // ---- phase 0: ks0, m-half 0 (B frags held for phase 1) ----
    LDB(bv[0], cur, 0, 0); LDB(bv[1], cur, 0, 1); LDB(bv[2], cur, 0, 2); LDB(bv[3], cur, 0, 3);
    LDA(av[0], cur, 0, 0); LDA(av[1], cur, 0, 1); LDA(av[2], cur, 0, 2); LDA(av[3], cur, 0, 3);
    if (hn) STAGE_A(nxt, 0, kc);
    BARX();
    __builtin_amdgcn_s_setprio(1);
    MFMA_HALF(0);
    __builtin_amdgcn_s_setprio(0);
    BARX();

    // ---- phase 1: ks0, m-half 1 ----
    LDA(av[0], cur, 0, 4); LDA(av[1], cur, 0, 5); LDA(av[2], cur, 0, 6); LDA(av[3], cur, 0, 7);
    if (hn) {
      STAGE_B(nxt, 0, kc);
      asm volatile("s_waitcnt vmcnt(4)" ::: "memory");  // A/B ks1(t) complete for phases 2,3
    } else {
      asm volatile("s_waitcnt vmcnt(0)" ::: "memory");  // final tile: drain
    }
    BARX();
    __builtin_amdgcn_s_setprio(1);
    MFMA_HALF(1);
    __builtin_amdgcn_s_setprio(0);
    BARX();

    // ---- phase 2: ks1, m-half 0 ----
    LDB(bv[0], cur, 1, 0); LDB(bv[1], cur, 1, 1); LDB(bv[2], cur, 1, 2); LDB(bv[3], cur, 1, 3);
    LDA(av[0], cur, 1, 0); LDA(av[1], cur, 1, 1); LDA(av[2], cur, 1, 2); LDA(av[3], cur, 1, 3);
    if (hn) STAGE_A(nxt, 1, kc);
    BARX();
    __builtin_amdgcn_s_setprio(1);
    MFMA_HALF(0);
    __builtin_amdgcn_s_setprio(0);
    BARX();

    // ---- phase 3: ks1, m-half 1 ----
    LDA(av[0], cur, 1, 4); LDA(av[1], cur, 1, 5); LDA(av[2], cur, 1, 6); LDA(av[3], cur, 1, 7);
    if (hn) {
      STAGE_B(nxt, 1, kc);
      asm volatile("s_waitcnt vmcnt(4)" ::: "memory");  // A/B ks0(t+1) complete for next ph0/1
    }
    BARX();
    __builtin_amdgcn_s_setprio(1);
    MFMA_HALF(1);
    __builtin_amdgcn_s_setprio(0);
    BARX();
  }

  __hip_bfloat16* C = Eo + (size_t)e * CAP * HD +
                      (size_t)(tm * 256 + wm * 128) * HD + tn * 256 + wn * 64;
#pragma unroll
  for (int m = 0; m < 8; ++m)
#pragma unroll
    for (int n = 0; n < 4; ++n)
#pragma unroll
      for (int r = 0; r < 4; ++r)
        C[(size_t)(m * 16 + fq * 4 + r) * HD + n * 16 + fr] = __float2bfloat16(acc[m][n][r]);
}

// ---------------- combine ----------------
__global__ __launch_bounds__(256) void combine_kernel(const __hip_bfloat16* __restrict__ eo,
                                                      const int* __restrict__ slot_of,
                                                      const float2* __restrict__ p01,
                                                      float* __restrict__ out) {
  const int t = blockIdx.x;
  const int tid = threadIdx.x;
  const float2 p = p01[t];
  const int s0 = slot_of[2 * t], s1 = slot_of[2 * t + 1];
  float a0 = 0.f, a1 = 0.f, a2 = 0.f, a3 = 0.f;
  if (s0 >= 0) {
    u16x4 v = *(const u16x4*)((const unsigned short*)eo + (size_t)s0 * HD + tid * 4);
    a0 += p.x * bf2f(v[0]); a1 += p.x * bf2f(v[1]);
    a2 += p.x * bf2f(v[2]); a3 += p.x * bf2f(v[3]);
  }
  if (s1 >= 0) {
    u16x4 v = *(const u16x4*)((const unsigned short*)eo + (size_t)s1 * HD + tid * 4);
    a0 += p.y * bf2f(v[0]); a1 += p.y * bf2f(v[1]);
    a2 += p.y * bf2f(v[2]); a3 += p.y * bf2f(v[3]);
  }
  float4 res = make_float4(a0, a1, a2, a3);
  *(float4*)(out + (size_t)t * HD + tid * 4) = res;
}

// ---------------- aux loss ----------------
__global__ __launch_bounds__(64) void aux_kernel(const float* __restrict__ imp_part,
                                                 const int* __restrict__ counts,
                                                 float* __restrict__ out) {
  const int e = threadIdx.x;
  float imp = 0.f;
  for (int w = 0; w < 512; ++w) imp += imp_part[(size_t)w * 64 + e];
  imp *= (1.f / (float)NTOK);
  float usage = (float)counts[e] / (float)NKF;
  float v = usage * imp;
#pragma unroll
  for (int off = 32; off; off >>= 1) v += __shfl_xor(v, off);
  if (e == 0) out[(size_t)NTOK * HD] = fminf(v * (float)NE * 0.01f, 1.0f);
}

extern "C" void kernel_launch(void* const* d_in, const int* in_sizes, int n_in,
                              void* d_out, int out_size, void* d_ws, size_t ws_size,
                              hipStream_t stream) {
  const float* x = (const float*)d_in[0];
  const float* gw = (const float*)d_in[1];
  const float* ew = (const float*)d_in[2];
  float* out = (float*)d_out;

  char* p = (char*)d_ws;
  float* logits = (float*)p;            p += (size_t)NTOK * NE * 4;
  int2* e01 = (int2*)p;                 p += (size_t)NTOK * 8;
  float2* p01 = (float2*)p;             p += (size_t)NTOK * 8;
  int* slot_of = (int*)p;               p += (size_t)NKF * 4;
  int* slot_token = (int*)p;            p += (size_t)NSLOT * 4;
  int* counts = (int*)p;                p += 256;
  float* imp_part = (float*)p;          p += (size_t)512 * 64 * 4;
  int* rank_buf = (int*)p;              p += (size_t)NKF * 4;
  int* hist = (int*)p;                  p += (size_t)NTILE * 64 * 4;
  int* tile_off = (int*)p;              p += (size_t)NTILE * 64 * 4;
  __hip_bfloat16* zp = (__hip_bfloat16*)p; p += 4096;
  __hip_bfloat16* xb = (__hip_bfloat16*)p; p += (size_t)NTOK * HD * 2;
  __hip_bfloat16* Wb = (__hip_bfloat16*)p;  p += (size_t)NE * HD * HD * 2;
  __hip_bfloat16* Eo = (__hip_bfloat16*)p;  p += (size_t)NSLOT * HD * 2;

  hipMemsetAsync(slot_token, 0xFF, (size_t)NSLOT * 4, stream);
  hipMemsetAsync(zp, 0, 4096, stream);

  convw_kernel<<<32768, 256, 0, stream>>>(ew, Wb);
  gating_kernel<<<NTOK / 64, 256, 0, stream>>>(x, gw, logits, xb);
  topk_kernel<<<NTOK / 256, 256, 0, stream>>>(logits, e01, p01, imp_part);
  hist_rank_kernel<<<NTILE, 256, 0, stream>>>(e01, rank_buf, hist);
  scan_kernel<<<1, 64, 0, stream>>>(hist, tile_off, counts);
  place_kernel<<<NTILE, 256, 0, stream>>>(e01, rank_buf, tile_off, slot_of, slot_token);
  moe_gemm_kernel<<<dim3(1280), 512, 0, stream>>>(xb, slot_token, Wb, zp, Eo);
  combine_kernel<<<NTOK, 256, 0, stream>>>(Eo, slot_of, p01, out);
  aux_kernel<<<1, 64, 0, stream>>>(imp_part, counts, out);
}